// Round 6
// baseline (355.580 us; speedup 1.0000x reference)
//
#include <hip/hip_runtime.h>
#include <math.h>

namespace {

constexpr int D  = 128;
constexpr int H  = 8;
constexpr int TN = 64;
constexpr int K2_ITERS = 8;    // batches per k2 block (software pipeline depth = 1)

// d_ws layout (requires ws_size >= 34.6 MB):
//   N  [128][1024] f32  (0.25 * WQ_h @ WK_h^T, stacked over h)   512 KB
//   M  [1024][128] f32  (WV_h @ WO_h, stacked over h)            512 KB
//   QS [B][1024]   f32  (qk, overwritten in-place by s in K2)     32 MB

// ---------------- K0: precompute N and M (tiny) ----------------
__global__ __launch_bounds__(256)
void k0_nm(const float* __restrict__ WQ, const float* __restrict__ WK,
           const float* __restrict__ WV, const float* __restrict__ WO,
           float* __restrict__ Nmat, float* __restrict__ Mmat)
{
    const int t = blockIdx.x * 256 + threadIdx.x;   // 0..131071
    {   // N[k][h*128+d] = 0.25 * sum_j WQ[k][h*16+j] * WK[d][h*16+j]
        const int k = t >> 10, col = t & 1023;
        const int h = col >> 7, d = col & 127;
        const float* wq = WQ + (size_t)k * D + h * 16;
        const float* wk = WK + (size_t)d * D + h * 16;
        float a = 0.f;
        #pragma unroll
        for (int j = 0; j < 16; ++j) a = fmaf(wq[j], wk[j], a);
        Nmat[t] = 0.25f * a;
    }
    {   // M[h*128+d][e] = sum_j WV[d][h*16+j] * WO[h*16+j][e]
        const int row = t >> 7, e = t & 127;
        const int h = row >> 7, d = row & 127;
        const float* wv = WV + (size_t)d * D + h * 16;
        const float* wo = WO + (size_t)(h * 16) * D + e;
        float a = 0.f;
        #pragma unroll
        for (int j = 0; j < 16; ++j) a = fmaf(wv[j], wo[(size_t)j * D], a);
        Mmat[t] = a;
    }
}

// ---------------- K1: qk = center @ N  ([8192,128]@[128,1024]), 16 rows/block ----------------
__global__ __launch_bounds__(256)
void k1_qk(const float* __restrict__ center, const float* __restrict__ Nmat,
           float* __restrict__ qk)
{
    __shared__ float c_lds[16 * 128];     // 8 KB
    const int tid = threadIdx.x;
    const size_t rb = (size_t)blockIdx.x * 16;

    const float4* cs = (const float4*)(center + rb * D);   // 512 f4
    ((float4*)c_lds)[tid]       = cs[tid];
    ((float4*)c_lds)[256 + tid] = cs[256 + tid];
    __syncthreads();

    const float4* Np = (const float4*)Nmat + tid;   // N row = 256 float4
    float4 acc[16];
    #pragma unroll
    for (int r = 0; r < 16; ++r) acc[r] = make_float4(0.f, 0.f, 0.f, 0.f);

    float4 bufA[4], bufB[4];
    #pragma unroll
    for (int i = 0; i < 4; ++i) bufA[i] = Np[(size_t)i * 256];

    #pragma unroll
    for (int g = 0; g < 32; ++g) {
        float4* cur = (g & 1) ? bufB : bufA;
        float4* nxt = (g & 1) ? bufA : bufB;
        if (g < 31) {
            #pragma unroll
            for (int i = 0; i < 4; ++i) nxt[i] = Np[(size_t)(g * 4 + 4 + i) * 256];
        }
        #pragma unroll
        for (int r = 0; r < 16; ++r) {
            const float4 cc = *reinterpret_cast<const float4*>(&c_lds[r * 128 + g * 4]);
            acc[r].x = fmaf(cc.x, cur[0].x, acc[r].x);
            acc[r].y = fmaf(cc.x, cur[0].y, acc[r].y);
            acc[r].z = fmaf(cc.x, cur[0].z, acc[r].z);
            acc[r].w = fmaf(cc.x, cur[0].w, acc[r].w);
            acc[r].x = fmaf(cc.y, cur[1].x, acc[r].x);
            acc[r].y = fmaf(cc.y, cur[1].y, acc[r].y);
            acc[r].z = fmaf(cc.y, cur[1].z, acc[r].z);
            acc[r].w = fmaf(cc.y, cur[1].w, acc[r].w);
            acc[r].x = fmaf(cc.z, cur[2].x, acc[r].x);
            acc[r].y = fmaf(cc.z, cur[2].y, acc[r].y);
            acc[r].z = fmaf(cc.z, cur[2].z, acc[r].z);
            acc[r].w = fmaf(cc.z, cur[2].w, acc[r].w);
            acc[r].x = fmaf(cc.w, cur[3].x, acc[r].x);
            acc[r].y = fmaf(cc.w, cur[3].y, acc[r].y);
            acc[r].z = fmaf(cc.w, cur[3].z, acc[r].z);
            acc[r].w = fmaf(cc.w, cur[3].w, acc[r].w);
        }
    }
    #pragma unroll
    for (int r = 0; r < 16; ++r)
        ((float4*)(qk + (rb + r) * 1024))[tid] = acc[r];
}

// ---------------- K2 v3: 128-thr block, 8 batches, register-staged prefetch pipeline --------
__global__ __launch_bounds__(128)
void k2_stream(const float* __restrict__ center, const float* __restrict__ neighbors,
               float* __restrict__ qs /* in: qk, out: s (in-place per batch) */)
{
    __shared__ float nb_lds[TN * D];       // 32 KB, f4-index: (t<<5) | (fc ^ (t&7))
    __shared__ float qk_lds[H * D];        // 4 KB; reused as s-partial buffer at the end
    __shared__ float P_lds[TN][8];         // 2 KB
    __shared__ float c_lds[D];             // 0.5 KB
    __shared__ float red[2][2][8];         // per-wave max/sum

    const int tid = threadIdx.x;           // 0..127
    const int w   = tid >> 6;              // wave 0/1
    const int l   = tid & 63;
    const int hi  = l >> 5;
    const int ll  = l & 31;

    // ---- preload batch 0 into staging registers ----
    float4 st[16];
    float4 qv0, qv1, cv = make_float4(0.f, 0.f, 0.f, 0.f);
    {
        const int b0 = blockIdx.x * K2_ITERS;
        const float4* gnb = (const float4*)(neighbors + (size_t)b0 * TN * D);
        #pragma unroll
        for (int i = 0; i < 16; ++i) st[i] = gnb[i * 128 + tid];
        const float4* qp = (const float4*)(qs + (size_t)b0 * 1024);
        qv0 = qp[tid];
        qv1 = qp[128 + tid];
        if (tid < 32) cv = ((const float4*)(center + (size_t)b0 * D))[tid];
    }

    for (int j = 0; j < K2_ITERS; ++j) {
        const int b = blockIdx.x * K2_ITERS + j;
        float* qsb = qs + (size_t)b * 1024;

        // ---- commit staged registers to LDS (vmcnt wait lands here) ----
        #pragma unroll
        for (int i = 0; i < 16; ++i) {
            const int fi = i * 128 + tid;
            const int t  = fi >> 5;
            const int fc = fi & 31;
            ((float4*)nb_lds)[(t << 5) | (fc ^ (t & 7))] = st[i];
        }
        ((float4*)qk_lds)[tid]       = qv0;
        ((float4*)qk_lds)[128 + tid] = qv1;
        if (tid < 32) ((float4*)c_lds)[tid] = cv;
        __syncthreads();

        // ---- issue next batch's loads now; they fly during compute ----
        if (j + 1 < K2_ITERS) {
            const int bn = b + 1;
            const float4* gn = (const float4*)(neighbors + (size_t)bn * TN * D);
            #pragma unroll
            for (int i = 0; i < 16; ++i) st[i] = gn[i * 128 + tid];
            const float4* qp = (const float4*)(qs + (size_t)bn * 1024);
            qv0 = qp[tid];
            qv1 = qp[128 + tid];
            if (tid < 32) cv = ((const float4*)(center + (size_t)bn * D))[tid];
        }
        asm volatile("" ::: "memory");   // keep the prefetch issue above the compute

        // ---- pass 1: wave w scores tokens w*32+ll; lane halves split d ----
        const int t1   = w * 32 + ll;
        const int t1rb = t1 << 5;
        const int t1sw = t1 & 7;
        float sc[8];
        #pragma unroll
        for (int h = 0; h < 8; ++h) sc[h] = 0.f;
        #pragma unroll
        for (int jj = 0; jj < 16; ++jj) {
            const int fc = hi * 16 + jj;
            const float4 tv = ((const float4*)nb_lds)[t1rb | (fc ^ t1sw)];
            #pragma unroll
            for (int h = 0; h < 8; ++h) {
                const float4 kv = ((const float4*)qk_lds)[h * 32 + fc];
                sc[h] = fmaf(tv.x, kv.x, fmaf(tv.y, kv.y, fmaf(tv.z, kv.z, fmaf(tv.w, kv.w, sc[h]))));
            }
        }
        #pragma unroll
        for (int h = 0; h < 8; ++h) sc[h] += __shfl_xor(sc[h], 32);   // combine d-halves

        // ---- center score s0[h] (both waves compute identically) ----
        float s0[8];
        {
            const float cx = c_lds[2 * l], cy = c_lds[2 * l + 1];
            #pragma unroll
            for (int h = 0; h < 8; ++h) {
                const float2 qq = *reinterpret_cast<const float2*>(&qk_lds[h * 128 + 2 * l]);
                float v = qq.x * cx + qq.y * cy;
                #pragma unroll
                for (int off = 32; off >= 1; off >>= 1) v += __shfl_xor(v, off);
                s0[h] = v;
            }
        }

        // ---- softmax over 65 tokens (2-wave combine via LDS) ----
        float mw[8];
        #pragma unroll
        for (int h = 0; h < 8; ++h) {
            float m = sc[h];
            #pragma unroll
            for (int off = 16; off >= 1; off >>= 1) m = fmaxf(m, __shfl_xor(m, off));
            mw[h] = m;
        }
        if (l == 0) {
            #pragma unroll
            for (int h = 0; h < 8; ++h) red[w][0][h] = mw[h];
        }
        __syncthreads();

        float pmy[8], pctr[8], e0[8], sw_[8];
        #pragma unroll
        for (int h = 0; h < 8; ++h) {
            const float m = fmaxf(fmaxf(red[0][0][h], red[1][0][h]), s0[h]);
            pmy[h] = __expf(sc[h] - m);
            e0[h]  = __expf(s0[h] - m);
            float s = pmy[h];
            #pragma unroll
            for (int off = 16; off >= 1; off >>= 1) s += __shfl_xor(s, off);
            sw_[h] = s;
        }
        if (l == 0) {
            #pragma unroll
            for (int h = 0; h < 8; ++h) red[w][1][h] = sw_[h];
        }
        __syncthreads();

        #pragma unroll
        for (int h = 0; h < 8; ++h) {
            const float inv = 1.0f / (red[0][1][h] + red[1][1][h] + e0[h]);
            pmy[h]  *= inv;
            pctr[h]  = e0[h] * inv;
        }
        if (hi == 0) {
            *reinterpret_cast<float4*>(&P_lds[t1][0]) = make_float4(pmy[0], pmy[1], pmy[2], pmy[3]);
            *reinterpret_cast<float4*>(&P_lds[t1][4]) = make_float4(pmy[4], pmy[5], pmy[6], pmy[7]);
        }
        __syncthreads();

        // ---- pass 2: wave w sums its 32 tokens; lane: col f4 = ll, hi splits 16+16 ----
        float4 acc[8];
        #pragma unroll
        for (int h = 0; h < 8; ++h) acc[h] = make_float4(0.f, 0.f, 0.f, 0.f);
        #pragma unroll
        for (int tt = 0; tt < 16; ++tt) {
            const int t2 = w * 32 + hi * 16 + tt;
            const float4 tv = ((const float4*)nb_lds)[(t2 << 5) | (ll ^ (t2 & 7))];
            const float4 pa = *reinterpret_cast<const float4*>(&P_lds[t2][0]);
            const float4 pb = *reinterpret_cast<const float4*>(&P_lds[t2][4]);
            const float p8[8] = {pa.x, pa.y, pa.z, pa.w, pb.x, pb.y, pb.z, pb.w};
            #pragma unroll
            for (int h = 0; h < 8; ++h) {
                acc[h].x = fmaf(p8[h], tv.x, acc[h].x);
                acc[h].y = fmaf(p8[h], tv.y, acc[h].y);
                acc[h].z = fmaf(p8[h], tv.z, acc[h].z);
                acc[h].w = fmaf(p8[h], tv.w, acc[h].w);
            }
        }
        #pragma unroll
        for (int h = 0; h < 8; ++h) {          // combine hi-halves
            acc[h].x += __shfl_xor(acc[h].x, 32);
            acc[h].y += __shfl_xor(acc[h].y, 32);
            acc[h].z += __shfl_xor(acc[h].z, 32);
            acc[h].w += __shfl_xor(acc[h].w, 32);
        }
        // cross-wave combine through qk_lds region (dead after softmax)
        if (w == 0 && hi == 0) {
            #pragma unroll
            for (int h = 0; h < 8; ++h) ((float4*)qk_lds)[h * 32 + ll] = acc[h];
        }
        __syncthreads();
        if (w == 1 && hi == 0) {
            const float4 cc = ((const float4*)c_lds)[ll];
            #pragma unroll
            for (int h = 0; h < 8; ++h) {
                const float4 p0 = ((const float4*)qk_lds)[h * 32 + ll];
                float4 o;
                o.x = p0.x + acc[h].x + pctr[h] * cc.x;
                o.y = p0.y + acc[h].y + pctr[h] * cc.y;
                o.z = p0.z + acc[h].z + pctr[h] * cc.z;
                o.w = p0.w + acc[h].w + pctr[h] * cc.w;
                *reinterpret_cast<float4*>(qsb + h * 128 + ll * 4) = o;
            }
        }
        __syncthreads();   // all LDS consumers done before next iteration overwrites
    }
}

// ---------------- K3: out = s @ M  ([8192,1024]@[1024,128]), 16 rows/block ----------------
__global__ __launch_bounds__(256)
void k3_out(const float* __restrict__ qs, const float* __restrict__ Mmat,
            float* __restrict__ out)
{
    __shared__ float s_lds[16 * 1024];  // 64 KB; reused as partial[8][16][128]
    const int tid = threadIdx.x;
    const size_t rb = (size_t)blockIdx.x * 16;

    {   // cooperative load of 16 s-rows
        const float4* sp = (const float4*)(qs + rb * 1024);
        #pragma unroll
        for (int i = 0; i < 16; ++i)
            ((float4*)s_lds)[i * 256 + tid] = sp[i * 256 + tid];
    }
    __syncthreads();

    const int cg = tid & 31;          // column group: cols cg*4..cg*4+3
    const int kg = tid >> 5;          // k-split group 0..7 (k-range kg*128..+127)
    const int c4 = cg << 2;
    const int kbase = kg << 7;

    float4 acc[16];
    #pragma unroll
    for (int r = 0; r < 16; ++r) acc[r] = make_float4(0.f, 0.f, 0.f, 0.f);

    const float4* Mp4 = (const float4*)Mmat;    // M row = 32 float4

    float4 bA[4], bB[4];
    #pragma unroll
    for (int i = 0; i < 4; ++i) bA[i] = Mp4[(size_t)(kbase + i) * 32 + cg];

    #pragma unroll
    for (int g = 0; g < 32; ++g) {
        float4* cur = (g & 1) ? bB : bA;
        float4* nxt = (g & 1) ? bA : bB;
        if (g < 31) {
            #pragma unroll
            for (int i = 0; i < 4; ++i)
                nxt[i] = Mp4[(size_t)(kbase + g * 4 + 4 + i) * 32 + cg];
        }
        #pragma unroll
        for (int r = 0; r < 16; ++r) {
            const float4 ss = *reinterpret_cast<const float4*>(&s_lds[r * 1024 + kbase + g * 4]);
            acc[r].x = fmaf(ss.x, cur[0].x, acc[r].x);
            acc[r].y = fmaf(ss.x, cur[0].y, acc[r].y);
            acc[r].z = fmaf(ss.x, cur[0].z, acc[r].z);
            acc[r].w = fmaf(ss.x, cur[0].w, acc[r].w);
            acc[r].x = fmaf(ss.y, cur[1].x, acc[r].x);
            acc[r].y = fmaf(ss.y, cur[1].y, acc[r].y);
            acc[r].z = fmaf(ss.y, cur[1].z, acc[r].z);
            acc[r].w = fmaf(ss.y, cur[1].w, acc[r].w);
            acc[r].x = fmaf(ss.z, cur[2].x, acc[r].x);
            acc[r].y = fmaf(ss.z, cur[2].y, acc[r].y);
            acc[r].z = fmaf(ss.z, cur[2].z, acc[r].z);
            acc[r].w = fmaf(ss.z, cur[2].w, acc[r].w);
            acc[r].x = fmaf(ss.w, cur[3].x, acc[r].x);
            acc[r].y = fmaf(ss.w, cur[3].y, acc[r].y);
            acc[r].z = fmaf(ss.w, cur[3].z, acc[r].z);
            acc[r].w = fmaf(ss.w, cur[3].w, acc[r].w);
        }
    }
    __syncthreads();                  // all s_lds reads done; reuse as partials
    float* part = s_lds;              // part[(kg*16 + r)*128 + c4]
    #pragma unroll
    for (int r = 0; r < 16; ++r)
        *reinterpret_cast<float4*>(&part[(kg * 16 + r) * 128 + c4]) = acc[r];
    __syncthreads();

    {   // reduce 8 partials; thread handles 2 rows x 4 cols
        #pragma unroll
        for (int rr = 0; rr < 2; ++rr) {
            const int r = (tid >> 5) * 2 + rr;
            float4 sum = make_float4(0.f, 0.f, 0.f, 0.f);
            #pragma unroll
            for (int g = 0; g < 8; ++g) {
                const float4 p = *reinterpret_cast<const float4*>(&part[(g * 16 + r) * 128 + c4]);
                sum.x += p.x; sum.y += p.y; sum.z += p.z; sum.w += p.w;
            }
            *reinterpret_cast<float4*>(out + (rb + r) * D + c4) = sum;
        }
    }
}

} // namespace

extern "C" void kernel_launch(void* const* d_in, const int* in_sizes, int n_in,
                              void* d_out, int out_size, void* d_ws, size_t ws_size,
                              hipStream_t stream) {
    const float* center    = (const float*)d_in[0];
    const float* neighbors = (const float*)d_in[1];
    const float* WQ        = (const float*)d_in[2];
    const float* WK        = (const float*)d_in[3];
    const float* WV        = (const float*)d_in[4];
    const float* WO        = (const float*)d_in[5];
    float* outp            = (float*)d_out;

    const int B = in_sizes[0] / D;   // 8192

    float* Nmat = (float*)d_ws;                 // 128*1024
    float* Mmat = Nmat + 128 * 1024;            // 1024*128
    float* QS   = Mmat + 1024 * 128;            // B*1024 (qk, then s in-place)
    // requires ws_size >= (262144 + B*1024)*4 = ~34.6 MB

    hipLaunchKernelGGL(k0_nm,    dim3(512),          dim3(256), 0, stream, WQ, WK, WV, WO, Nmat, Mmat);
    hipLaunchKernelGGL(k1_qk,    dim3(B / 16),       dim3(256), 0, stream, center, Nmat, QS);
    hipLaunchKernelGGL(k2_stream,dim3(B / K2_ITERS), dim3(128), 0, stream, center, neighbors, QS);
    hipLaunchKernelGGL(k3_out,   dim3(B / 16),       dim3(256), 0, stream, QS, Mmat, outp);
}

// Round 7
// 208.949 us; speedup vs baseline: 1.7018x; 1.7018x over previous
//
#include <hip/hip_runtime.h>
#include <math.h>

namespace {

constexpr int D  = 128;
constexpr int H  = 8;
constexpr int TN = 64;

// d_ws layout (requires ws_size >= 34.6 MB):
//   N  [128][1024] f32  (0.25 * WQ_h @ WK_h^T, stacked over h)   512 KB
//   M  [1024][128] f32  (WV_h @ WO_h, stacked over h)            512 KB
//   QS [B][1024]   f32  (qk, overwritten in-place by s in K2)     32 MB

// ---------------- K0: precompute N and M (tiny) ----------------
__global__ __launch_bounds__(256)
void k0_nm(const float* __restrict__ WQ, const float* __restrict__ WK,
           const float* __restrict__ WV, const float* __restrict__ WO,
           float* __restrict__ Nmat, float* __restrict__ Mmat)
{
    const int t = blockIdx.x * 256 + threadIdx.x;   // 0..131071
    {   // N[k][h*128+d] = 0.25 * sum_j WQ[k][h*16+j] * WK[d][h*16+j]
        const int k = t >> 10, col = t & 1023;
        const int h = col >> 7, d = col & 127;
        const float* wq = WQ + (size_t)k * D + h * 16;
        const float* wk = WK + (size_t)d * D + h * 16;
        float a = 0.f;
        #pragma unroll
        for (int j = 0; j < 16; ++j) a = fmaf(wq[j], wk[j], a);
        Nmat[t] = 0.25f * a;
    }
    {   // M[h*128+d][e] = sum_j WV[d][h*16+j] * WO[h*16+j][e]
        const int row = t >> 7, e = t & 127;
        const int h = row >> 7, d = row & 127;
        const float* wv = WV + (size_t)d * D + h * 16;
        const float* wo = WO + (size_t)(h * 16) * D + e;
        float a = 0.f;
        #pragma unroll
        for (int j = 0; j < 16; ++j) a = fmaf(wv[j], wo[(size_t)j * D], a);
        Mmat[t] = a;
    }
}

// ---------------- K1: qk = center @ N  ([8192,128]@[128,1024]), 8 rows/block (r4 proven) ----
__global__ __launch_bounds__(256)
void k1_qk(const float* __restrict__ center, const float* __restrict__ Nmat,
           float* __restrict__ qk)
{
    __shared__ float c_lds[8 * 128];      // 8 center rows
    const int tid = threadIdx.x;
    const size_t rb = (size_t)blockIdx.x * 8;

    ((float4*)c_lds)[tid] = ((const float4*)(center + rb * D))[tid];
    __syncthreads();

    const float4* Np = (const float4*)Nmat + tid;   // N row = 256 float4
    float4 acc[8];
    #pragma unroll
    for (int r = 0; r < 8; ++r) acc[r] = make_float4(0.f, 0.f, 0.f, 0.f);

    float4 bufA[4], bufB[4];
    #pragma unroll
    for (int i = 0; i < 4; ++i) bufA[i] = Np[(size_t)i * 256];

    #pragma unroll
    for (int g = 0; g < 32; ++g) {
        float4* cur = (g & 1) ? bufB : bufA;
        float4* nxt = (g & 1) ? bufA : bufB;
        if (g < 31) {
            #pragma unroll
            for (int i = 0; i < 4; ++i) nxt[i] = Np[(size_t)(g * 4 + 4 + i) * 256];
        }
        #pragma unroll
        for (int i = 0; i < 4; ++i) {
            const int k = g * 4 + i;
            const float4 nv = cur[i];
            #pragma unroll
            for (int r = 0; r < 8; ++r) {
                const float cc = c_lds[r * 128 + k];
                acc[r].x = fmaf(cc, nv.x, acc[r].x);
                acc[r].y = fmaf(cc, nv.y, acc[r].y);
                acc[r].z = fmaf(cc, nv.z, acc[r].z);
                acc[r].w = fmaf(cc, nv.w, acc[r].w);
            }
        }
    }
    #pragma unroll
    for (int r = 0; r < 8; ++r)
        ((float4*)(qk + (rb + r) * 1024))[tid] = acc[r];
}

// ---------------- K2 v4: 256-thr block per batch; 4-wave split; no reg pipeline -------------
// LDS ~38.8 KB -> 4 blocks/CU = 16 waves/CU. Overlap via TLP across blocks.
__global__ __launch_bounds__(256)
void k2_stream(const float* __restrict__ center, const float* __restrict__ neighbors,
               float* __restrict__ qs /* in: qk, out: s (in-place per batch) */)
{
    __shared__ float nb_lds[TN * D];       // 32 KB, f4-index: (t<<5) | (fc ^ (t&7))
    __shared__ float qk_lds[H * D];        // 4 KB
    __shared__ float P_lds[TN][8];         // 2 KB
    __shared__ float c_lds[D];             // 0.5 KB
    __shared__ float red[4][2][8];         // per-wave max/sum (256 B)

    const int tid = threadIdx.x;           // 0..255
    const int w   = tid >> 6;              // wave 0..3
    const int l   = tid & 63;
    const int b   = blockIdx.x;

    float*        qsb = qs + (size_t)b * 1024;
    const float4* gnb = (const float4*)(neighbors + (size_t)b * TN * D);

    // ---- stage: 8 f4/thread, fully coalesced (each instr = 4KB contiguous per wavegroup) ----
    float4 st[8];
    #pragma unroll
    for (int i = 0; i < 8; ++i) st[i] = gnb[i * 256 + tid];
    const float4 qv = ((const float4*)qsb)[tid];
    float4 cv;
    if (tid < 32) cv = ((const float4*)(center + (size_t)b * D))[tid];

    #pragma unroll
    for (int i = 0; i < 8; ++i) {
        const int fi = i * 256 + tid;      // global f4 index 0..2047
        const int t  = fi >> 5;            // token row
        const int fc = fi & 31;            // f4 col
        ((float4*)nb_lds)[(t << 5) | (fc ^ (t & 7))] = st[i];
    }
    ((float4*)qk_lds)[tid] = qv;
    if (tid < 32) ((float4*)c_lds)[tid] = cv;
    __syncthreads();

    // ---- pass 1: wave w scores tokens w*16+(l&15); quarters q=l>>4 split d (8 f4 each) ----
    const int tq = l & 15;                 // token within wave
    const int q  = l >> 4;                 // d-quarter
    const int t1 = w * 16 + tq;
    const int t1rb = t1 << 5;
    const int t1sw = t1 & 7;
    float sc[8];
    #pragma unroll
    for (int h = 0; h < 8; ++h) sc[h] = 0.f;
    #pragma unroll
    for (int jj = 0; jj < 8; ++jj) {
        const int fc = q * 8 + jj;
        const float4 tv = ((const float4*)nb_lds)[t1rb | (fc ^ t1sw)];
        #pragma unroll
        for (int h = 0; h < 8; ++h) {
            const float4 kv = ((const float4*)qk_lds)[h * 32 + fc];
            sc[h] = fmaf(tv.x, kv.x, fmaf(tv.y, kv.y, fmaf(tv.z, kv.z, fmaf(tv.w, kv.w, sc[h]))));
        }
    }
    #pragma unroll
    for (int h = 0; h < 8; ++h) {          // combine the 4 d-quarters
        sc[h] += __shfl_xor(sc[h], 16);
        sc[h] += __shfl_xor(sc[h], 32);
    }

    // ---- center score s0[h] (each wave computes identically) ----
    float s0[8];
    {
        const float cx = c_lds[2 * l], cy = c_lds[2 * l + 1];
        #pragma unroll
        for (int h = 0; h < 8; ++h) {
            const float2 qq = *reinterpret_cast<const float2*>(&qk_lds[h * 128 + 2 * l]);
            float v = qq.x * cx + qq.y * cy;
            #pragma unroll
            for (int off = 32; off >= 1; off >>= 1) v += __shfl_xor(v, off);
            s0[h] = v;
        }
    }

    // ---- softmax over 65 tokens (4-wave combine via LDS) ----
    float mw[8];
    #pragma unroll
    for (int h = 0; h < 8; ++h) {          // max over the wave's 16 tokens
        float m = sc[h];
        #pragma unroll
        for (int off = 8; off >= 1; off >>= 1) m = fmaxf(m, __shfl_xor(m, off));
        mw[h] = m;
    }
    if (l == 0) {
        #pragma unroll
        for (int h = 0; h < 8; ++h) red[w][0][h] = mw[h];
    }
    __syncthreads();

    float pmy[8], pctr[8], e0[8], sw_[8];
    #pragma unroll
    for (int h = 0; h < 8; ++h) {
        const float m = fmaxf(fmaxf(fmaxf(red[0][0][h], red[1][0][h]),
                                    fmaxf(red[2][0][h], red[3][0][h])), s0[h]);
        pmy[h] = __expf(sc[h] - m);
        e0[h]  = __expf(s0[h] - m);
        float s = pmy[h];
        #pragma unroll
        for (int off = 8; off >= 1; off >>= 1) s += __shfl_xor(s, off);
        sw_[h] = s;
    }
    if (l == 0) {
        #pragma unroll
        for (int h = 0; h < 8; ++h) red[w][1][h] = sw_[h];
    }
    __syncthreads();

    #pragma unroll
    for (int h = 0; h < 8; ++h) {
        const float inv = 1.0f / (red[0][1][h] + red[1][1][h] + red[2][1][h]
                                  + red[3][1][h] + e0[h]);
        pmy[h]  *= inv;
        pctr[h]  = e0[h] * inv;
    }
    if (l < 16) {
        *reinterpret_cast<float4*>(&P_lds[t1][0]) = make_float4(pmy[0], pmy[1], pmy[2], pmy[3]);
        *reinterpret_cast<float4*>(&P_lds[t1][4]) = make_float4(pmy[4], pmy[5], pmy[6], pmy[7]);
    }
    __syncthreads();

    // ---- pass 2: wave w owns f4 cols w*8..w*8+7; lanes split 64 tokens 8 ways ----
    const int cl = l & 7;                  // col within wave's range
    const int ti = l >> 3;                 // token-octet index
    const int fc2 = w * 8 + cl;
    float4 acc[8];
    #pragma unroll
    for (int h = 0; h < 8; ++h) acc[h] = make_float4(0.f, 0.f, 0.f, 0.f);
    #pragma unroll
    for (int tt = 0; tt < 8; ++tt) {
        const int t2 = ti * 8 + tt;        // t2 & 7 == tt
        const float4 tv = ((const float4*)nb_lds)[(t2 << 5) | (fc2 ^ tt)];
        const float4 pa = *reinterpret_cast<const float4*>(&P_lds[t2][0]);
        const float4 pb = *reinterpret_cast<const float4*>(&P_lds[t2][4]);
        const float p8[8] = {pa.x, pa.y, pa.z, pa.w, pb.x, pb.y, pb.z, pb.w};
        #pragma unroll
        for (int h = 0; h < 8; ++h) {
            acc[h].x = fmaf(p8[h], tv.x, acc[h].x);
            acc[h].y = fmaf(p8[h], tv.y, acc[h].y);
            acc[h].z = fmaf(p8[h], tv.z, acc[h].z);
            acc[h].w = fmaf(p8[h], tv.w, acc[h].w);
        }
    }
    #pragma unroll
    for (int h = 0; h < 8; ++h) {          // combine the 8 token-octet groups
        #pragma unroll
        for (int off = 8; off <= 32; off <<= 1) {
            acc[h].x += __shfl_xor(acc[h].x, off);
            acc[h].y += __shfl_xor(acc[h].y, off);
            acc[h].z += __shfl_xor(acc[h].z, off);
            acc[h].w += __shfl_xor(acc[h].w, off);
        }
    }
    if (ti == 0) {                         // lanes 0..7: write cols fc2, + center seed
        const float4 cc = ((const float4*)c_lds)[fc2];
        #pragma unroll
        for (int h = 0; h < 8; ++h) {
            float4 o;
            o.x = acc[h].x + pctr[h] * cc.x;
            o.y = acc[h].y + pctr[h] * cc.y;
            o.z = acc[h].z + pctr[h] * cc.z;
            o.w = acc[h].w + pctr[h] * cc.w;
            *reinterpret_cast<float4*>(qsb + h * 128 + fc2 * 4) = o;
        }
    }
}

// ---------------- K3: out = s @ M  ([8192,1024]@[1024,128]), 8 rows/block (r4 proven) -------
__global__ __launch_bounds__(256)
void k3_out(const float* __restrict__ qs, const float* __restrict__ Mmat,
            float* __restrict__ out)
{
    __shared__ float s_lds[8 * 1024];   // 32 KB; reused as partial[8][8][128]
    const int tid = threadIdx.x;
    const size_t rb = (size_t)blockIdx.x * 8;

    {   // cooperative load of 8 s-rows
        const float4* sp = (const float4*)(qs + rb * 1024);
        #pragma unroll
        for (int i = 0; i < 8; ++i)
            ((float4*)s_lds)[i * 256 + tid] = sp[i * 256 + tid];
    }
    __syncthreads();

    const int cg = tid & 31;          // column group: cols cg*4..cg*4+3
    const int kg = tid >> 5;          // k-split group 0..7
    const int c4 = cg << 2;
    const int kbase = kg << 7;
    const int rot = kg << 2;          // stagger groups across banks

    float4 acc[8];
    #pragma unroll
    for (int r = 0; r < 8; ++r) acc[r] = make_float4(0.f, 0.f, 0.f, 0.f);

    const float4* Mp4 = (const float4*)Mmat;    // M row = 32 float4

    float4 bA[4], bB[4];
    #pragma unroll
    for (int i = 0; i < 4; ++i) {
        const int k = kbase + ((0 * 4 + i + rot) & 127);
        bA[i] = Mp4[(size_t)k * 32 + cg];
    }
    #pragma unroll
    for (int g = 0; g < 32; ++g) {
        float4* cur = (g & 1) ? bB : bA;
        float4* nxt = (g & 1) ? bA : bB;
        if (g < 31) {
            #pragma unroll
            for (int i = 0; i < 4; ++i) {
                const int k = kbase + ((g * 4 + 4 + i + rot) & 127);
                nxt[i] = Mp4[(size_t)k * 32 + cg];
            }
        }
        #pragma unroll
        for (int i = 0; i < 4; ++i) {
            const int k = kbase + ((g * 4 + i + rot) & 127);
            const float4 mv = cur[i];
            #pragma unroll
            for (int r = 0; r < 8; ++r) {
                const float sv = s_lds[r * 1024 + k];
                acc[r].x = fmaf(sv, mv.x, acc[r].x);
                acc[r].y = fmaf(sv, mv.y, acc[r].y);
                acc[r].z = fmaf(sv, mv.z, acc[r].z);
                acc[r].w = fmaf(sv, mv.w, acc[r].w);
            }
        }
    }
    __syncthreads();                  // all s_lds reads done; reuse as partials
    float* part = s_lds;              // part[kg][r][128]
    #pragma unroll
    for (int r = 0; r < 8; ++r)
        *reinterpret_cast<float4*>(&part[(kg * 8 + r) * 128 + c4]) = acc[r];
    __syncthreads();

    {   // reduce 8 partials; thread -> (row r = tid>>5, cols c4)
        const int r = tid >> 5;
        float4 sum = make_float4(0.f, 0.f, 0.f, 0.f);
        #pragma unroll
        for (int g = 0; g < 8; ++g) {
            const float4 p = *reinterpret_cast<const float4*>(&part[(g * 8 + r) * 128 + c4]);
            sum.x += p.x; sum.y += p.y; sum.z += p.z; sum.w += p.w;
        }
        *reinterpret_cast<float4*>(out + (rb + r) * D + c4) = sum;
    }
}

} // namespace

extern "C" void kernel_launch(void* const* d_in, const int* in_sizes, int n_in,
                              void* d_out, int out_size, void* d_ws, size_t ws_size,
                              hipStream_t stream) {
    const float* center    = (const float*)d_in[0];
    const float* neighbors = (const float*)d_in[1];
    const float* WQ        = (const float*)d_in[2];
    const float* WK        = (const float*)d_in[3];
    const float* WV        = (const float*)d_in[4];
    const float* WO        = (const float*)d_in[5];
    float* outp            = (float*)d_out;

    const int B = in_sizes[0] / D;   // 8192

    float* Nmat = (float*)d_ws;                 // 128*1024
    float* Mmat = Nmat + 128 * 1024;            // 1024*128
    float* QS   = Mmat + 1024 * 128;            // B*1024 (qk, then s in-place)
    // requires ws_size >= (262144 + B*1024)*4 = ~34.6 MB

    hipLaunchKernelGGL(k0_nm,    dim3(512),   dim3(256), 0, stream, WQ, WK, WV, WO, Nmat, Mmat);
    hipLaunchKernelGGL(k1_qk,    dim3(B / 8), dim3(256), 0, stream, center, Nmat, QS);
    hipLaunchKernelGGL(k2_stream,dim3(B),     dim3(256), 0, stream, center, neighbors, QS);
    hipLaunchKernelGGL(k3_out,   dim3(B / 8), dim3(256), 0, stream, QS, Mmat, outp);
}